// Round 1
// baseline (586.495 us; speedup 1.0000x reference)
//
#include <hip/hip_runtime.h>
#include <math.h>

// ---------------- CSR build ----------------

__global__ __launch_bounds__(256) void init_k(float* deg, int* cnt, int* cursor, int n) {
    int i = blockIdx.x * 256 + threadIdx.x;
    if (i < n) { deg[i] = 1.0f; cnt[i] = 0; cursor[i] = 0; }
}

__global__ __launch_bounds__(256) void hist_k(const int* __restrict__ src, const int* __restrict__ dst,
                                              const float* __restrict__ ew,
                                              float* deg, int* cnt, int E) {
    int e = blockIdx.x * 256 + threadIdx.x;
    if (e < E) {
        int d = dst[e];
        atomicAdd(&deg[d], ew[e]);
        atomicAdd(&cnt[d], 1);
        (void)src;
    }
}

__global__ __launch_bounds__(256) void scan1_k(const int* __restrict__ cnt, int* bsum, int n) {
    __shared__ int sdata[256];
    int base = blockIdx.x * 1024;
    int t = threadIdx.x;
    int s = 0;
    #pragma unroll
    for (int j = 0; j < 4; j++) {
        int i = base + t * 4 + j;
        if (i < n) s += cnt[i];
    }
    sdata[t] = s;
    __syncthreads();
    for (int off = 128; off > 0; off >>= 1) {
        if (t < off) sdata[t] += sdata[t + off];
        __syncthreads();
    }
    if (t == 0) bsum[blockIdx.x] = sdata[0];
}

__global__ void scan2_k(int* bsum, int nb) {
    if (threadIdx.x == 0 && blockIdx.x == 0) {
        int run = 0;
        for (int b = 0; b < nb; b++) { int v = bsum[b]; bsum[b] = run; run += v; }
    }
}

__global__ __launch_bounds__(256) void scan3_k(const int* __restrict__ cnt, const int* __restrict__ bsum,
                                               int* row_ptr, int n) {
    __shared__ int sdata[256];
    int base = blockIdx.x * 1024;
    int t = threadIdx.x;
    int loc[4];
    int s = 0;
    #pragma unroll
    for (int j = 0; j < 4; j++) {
        int i = base + t * 4 + j;
        loc[j] = (i < n) ? cnt[i] : 0;
        s += loc[j];
    }
    sdata[t] = s;
    __syncthreads();
    // inclusive Hillis-Steele scan over 256 thread-sums
    for (int off = 1; off < 256; off <<= 1) {
        int v = (t >= off) ? sdata[t - off] : 0;
        __syncthreads();
        sdata[t] += v;
        __syncthreads();
    }
    int excl = sdata[t] - s;  // exclusive prefix for this thread
    int run = bsum[blockIdx.x] + excl;
    #pragma unroll
    for (int j = 0; j < 4; j++) {
        int i = base + t * 4 + j;
        if (i < n) row_ptr[i] = run;
        run += loc[j];
    }
}

__global__ __launch_bounds__(256) void dinv_k(float* deg, int n) {
    int i = blockIdx.x * 256 + threadIdx.x;
    if (i < n) deg[i] = rsqrtf(deg[i]);   // deg >= 1 always (self loop)
}

__global__ __launch_bounds__(256) void fill_k(const int* __restrict__ src, const int* __restrict__ dst,
                                              const float* __restrict__ ew, const float* __restrict__ dinv,
                                              const int* __restrict__ row_ptr, int* cursor,
                                              int2* __restrict__ meta, int E) {
    int e = blockIdx.x * 256 + threadIdx.x;
    if (e < E) {
        int d = dst[e];
        int s = src[e];
        int pos = row_ptr[d] + atomicAdd(&cursor[d], 1);
        float wn = dinv[s] * ew[e];           // dinv[dst] factored out at agg time
        meta[pos] = make_int2(s, __float_as_int(wn));
    }
}

// ---------------- fp32 GEMM: T[M,128] = A[M,K] @ W[K,128] ----------------
// BM=64, BN=128, BK=64, 256 threads, each thread 8x4 outputs.

__global__ __launch_bounds__(256) void gemm_k(const float* __restrict__ A, const float* __restrict__ W,
                                              float* __restrict__ T, int M, int K) {
    __shared__ float xs[64][68];   // +4 pad: bank-spread rows, keeps 16B alignment
    __shared__ float ws[64][128];
    int tid = threadIdx.x;
    int row0 = blockIdx.x * 64;
    int tx = tid & 31;   // cols tx*4 .. tx*4+3
    int ty = tid >> 5;   // rows ty*8 .. ty*8+7
    float acc[8][4] = {};

    for (int k0 = 0; k0 < K; k0 += 64) {
        // stage A tile 64x64
        #pragma unroll
        for (int j = 0; j < 4; j++) {
            int idx = tid + j * 256;        // 0..1023 float4 slots
            int r = idx >> 4;               // 16 float4 per row
            int c = (idx & 15) << 2;
            int gr = row0 + r;
            float4 v = make_float4(0.f, 0.f, 0.f, 0.f);
            if (gr < M) v = *(const float4*)(A + (size_t)gr * K + k0 + c);
            *(float4*)(&xs[r][c]) = v;
        }
        // stage W tile 64x128
        #pragma unroll
        for (int j = 0; j < 8; j++) {
            int idx = tid + j * 256;        // 0..2047 float4 slots
            int kk = idx >> 5;
            int c = (idx & 31) << 2;
            *(float4*)(&ws[kk][c]) = *(const float4*)(W + (size_t)(k0 + kk) * 128 + c);
        }
        __syncthreads();
        #pragma unroll 8
        for (int k = 0; k < 64; k++) {
            float4 b = *(const float4*)(&ws[k][tx << 2]);
            float a[8];
            #pragma unroll
            for (int r = 0; r < 8; r++) a[r] = xs[ty * 8 + r][k];
            #pragma unroll
            for (int r = 0; r < 8; r++) {
                acc[r][0] = fmaf(a[r], b.x, acc[r][0]);
                acc[r][1] = fmaf(a[r], b.y, acc[r][1]);
                acc[r][2] = fmaf(a[r], b.z, acc[r][2]);
                acc[r][3] = fmaf(a[r], b.w, acc[r][3]);
            }
        }
        __syncthreads();
    }
    #pragma unroll
    for (int r = 0; r < 8; r++) {
        int gr = row0 + ty * 8 + r;
        if (gr < M) *(float4*)(T + (size_t)gr * 128 + (tx << 2)) = *(float4*)(acc[r]);
    }
}

// ---------------- aggregation + bias + relu ----------------
// out[d] = relu( nd * (nd*t[d] + sum_j wn_j * t[src_j]) + bias )

__global__ __launch_bounds__(128) void agg_k(const float* __restrict__ T, float* __restrict__ H,
                                             const int2* __restrict__ meta,
                                             const int* __restrict__ row_ptr, const int* __restrict__ cnt,
                                             const float* __restrict__ dinv, const float* __restrict__ bias,
                                             int n) {
    int d = blockIdx.x;
    int f = threadIdx.x;
    float nd = dinv[d];
    float acc = nd * T[(size_t)d * 128 + f];
    int start = row_ptr[d];
    int c = cnt[d];
    int j = 0;
    for (; j + 1 < c; j += 2) {
        int2 m0 = meta[start + j];
        int2 m1 = meta[start + j + 1];
        float t0 = T[(size_t)m0.x * 128 + f];
        float t1 = T[(size_t)m1.x * 128 + f];
        acc = fmaf(__int_as_float(m0.y), t0, acc);
        acc = fmaf(__int_as_float(m1.y), t1, acc);
    }
    if (j < c) {
        int2 m0 = meta[start + j];
        acc = fmaf(__int_as_float(m0.y), T[(size_t)m0.x * 128 + f], acc);
    }
    float v = fmaf(nd, acc, bias[f]);
    H[(size_t)d * 128 + f] = v > 0.f ? v : 0.f;
}

// ---------------- final FC(128->10) + softmax ----------------

__global__ __launch_bounds__(256) void fc_k(const float* __restrict__ Hb, const float* __restrict__ FW,
                                            const float* __restrict__ FB, float* __restrict__ out, int n) {
    __shared__ float fw[128 * 10];
    __shared__ float fb[16];
    int tid = threadIdx.x;
    for (int i = tid; i < 128 * 10; i += 256) fw[i] = FW[i];
    if (tid < 10) fb[tid] = FB[tid];
    __syncthreads();
    int wave = tid >> 6, lane = tid & 63;
    int r = blockIdx.x * 4 + wave;
    if (r >= n) return;
    float h0 = Hb[(size_t)r * 128 + lane];
    float h1 = Hb[(size_t)r * 128 + 64 + lane];
    float p[10];
    #pragma unroll
    for (int c = 0; c < 10; c++)
        p[c] = h0 * fw[lane * 10 + c] + h1 * fw[(64 + lane) * 10 + c];
    #pragma unroll
    for (int off = 32; off > 0; off >>= 1) {
        #pragma unroll
        for (int c = 0; c < 10; c++) p[c] += __shfl_xor(p[c], off);
    }
    float m = -1e30f;
    #pragma unroll
    for (int c = 0; c < 10; c++) { p[c] += fb[c]; m = fmaxf(m, p[c]); }
    float s = 0.f;
    float e[10];
    #pragma unroll
    for (int c = 0; c < 10; c++) { e[c] = __expf(p[c] - m); s += e[c]; }
    float inv = 1.f / s;
    if (lane < 10) out[(size_t)r * 10 + lane] = e[lane] * inv;
}

// ---------------- host ----------------

extern "C" void kernel_launch(void* const* d_in, const int* in_sizes, int n_in,
                              void* d_out, int out_size, void* d_ws, size_t ws_size,
                              hipStream_t stream) {
    const float* x  = (const float*)d_in[0];
    const int*   ei = (const int*)d_in[1];
    const float* ew = (const float*)d_in[2];
    const float* W1 = (const float*)d_in[3];
    const float* b1 = (const float*)d_in[4];
    const float* W2 = (const float*)d_in[5];
    const float* b2 = (const float*)d_in[6];
    const float* W3 = (const float*)d_in[7];
    const float* b3 = (const float*)d_in[8];
    const float* FW = (const float*)d_in[9];
    const float* FB = (const float*)d_in[10];
    float* out = (float*)d_out;

    int Hd = in_sizes[4];            // 128
    int F  = in_sizes[3] / Hd;       // 256
    int N  = in_sizes[0] / F;        // 50000
    int E  = in_sizes[1] / 2;        // 800000

    const int* src = ei;
    const int* dst = ei + E;

    char* ws = (char*)d_ws;
    size_t off = 0;
    auto alloc = [&](size_t bytes) -> void* {
        void* p = ws + off;
        off = (off + bytes + 255) & ~(size_t)255;
        return p;
    };
    float* deg     = (float*)alloc((size_t)N * 4);   // becomes dinv in-place
    int*   cnt     = (int*)alloc((size_t)N * 4);
    int*   cursor  = (int*)alloc((size_t)N * 4);
    int*   row_ptr = (int*)alloc((size_t)N * 4);
    int*   bsum    = (int*)alloc(4096);
    int2*  meta    = (int2*)alloc((size_t)E * 8);
    float* T       = (float*)alloc((size_t)N * Hd * 4);
    float* Hbuf    = (float*)alloc((size_t)N * Hd * 4);

    int nb = (N + 1023) / 1024;

    init_k<<<(N + 255) / 256, 256, 0, stream>>>(deg, cnt, cursor, N);
    hist_k<<<(E + 255) / 256, 256, 0, stream>>>(src, dst, ew, deg, cnt, E);
    scan1_k<<<nb, 256, 0, stream>>>(cnt, bsum, N);
    scan2_k<<<1, 64, 0, stream>>>(bsum, nb);
    scan3_k<<<nb, 256, 0, stream>>>(cnt, bsum, row_ptr, N);
    dinv_k<<<(N + 255) / 256, 256, 0, stream>>>(deg, N);
    fill_k<<<(E + 255) / 256, 256, 0, stream>>>(src, dst, ew, deg, row_ptr, cursor, meta, E);

    int gb = (N + 63) / 64;
    // layer 1
    gemm_k<<<gb, 256, 0, stream>>>(x, W1, T, N, F);
    agg_k<<<N, 128, 0, stream>>>(T, Hbuf, meta, row_ptr, cnt, deg, b1, N);
    // layer 2
    gemm_k<<<gb, 256, 0, stream>>>(Hbuf, W2, T, N, Hd);
    agg_k<<<N, 128, 0, stream>>>(T, Hbuf, meta, row_ptr, cnt, deg, b2, N);
    // layer 3
    gemm_k<<<gb, 256, 0, stream>>>(Hbuf, W3, T, N, Hd);
    agg_k<<<N, 128, 0, stream>>>(T, Hbuf, meta, row_ptr, cnt, deg, b3, N);
    // FC + softmax
    fc_k<<<(N + 3) / 4, 256, 0, stream>>>(Hbuf, FW, FB, out, N);
}

// Round 2
// 529.310 us; speedup vs baseline: 1.1080x; 1.1080x over previous
//
#include <hip/hip_runtime.h>
#include <math.h>

// ---------------- CSR build (single-atomic counting sort) ----------------

// rank[e] = arrival order of edge e within its dst bin; cnt[d] = in-degree count
__global__ __launch_bounds__(256) void rank_k(const int* __restrict__ dst, int* cnt,
                                              int* __restrict__ rank, int E) {
    int e = blockIdx.x * 256 + threadIdx.x;
    if (e < E) {
        int d = dst[e];
        rank[e] = atomicAdd(&cnt[d], 1);
    }
}

__global__ __launch_bounds__(256) void scan1_k(const int* __restrict__ cnt, int* bsum, int n) {
    __shared__ int sdata[256];
    int base = blockIdx.x * 1024;
    int t = threadIdx.x;
    int s = 0;
    #pragma unroll
    for (int j = 0; j < 4; j++) {
        int i = base + t * 4 + j;
        if (i < n) s += cnt[i];
    }
    sdata[t] = s;
    __syncthreads();
    for (int off = 128; off > 0; off >>= 1) {
        if (t < off) sdata[t] += sdata[t + off];
        __syncthreads();
    }
    if (t == 0) bsum[blockIdx.x] = sdata[0];
}

__global__ void scan2_k(int* bsum, int nb) {
    if (threadIdx.x == 0 && blockIdx.x == 0) {
        int run = 0;
        for (int b = 0; b < nb; b++) { int v = bsum[b]; bsum[b] = run; run += v; }
    }
}

__global__ __launch_bounds__(256) void scan3_k(const int* __restrict__ cnt, const int* __restrict__ bsum,
                                               int* row_ptr, int n) {
    __shared__ int sdata[256];
    int base = blockIdx.x * 1024;
    int t = threadIdx.x;
    int loc[4];
    int s = 0;
    #pragma unroll
    for (int j = 0; j < 4; j++) {
        int i = base + t * 4 + j;
        loc[j] = (i < n) ? cnt[i] : 0;
        s += loc[j];
    }
    sdata[t] = s;
    __syncthreads();
    for (int off = 1; off < 256; off <<= 1) {
        int v = (t >= off) ? sdata[t - off] : 0;
        __syncthreads();
        sdata[t] += v;
        __syncthreads();
    }
    int excl = sdata[t] - s;
    int run = bsum[blockIdx.x] + excl;
    #pragma unroll
    for (int j = 0; j < 4; j++) {
        int i = base + t * 4 + j;
        if (i < n) row_ptr[i] = run;
        run += loc[j];
    }
}

// atomic-free fill: pos = row_ptr[dst] + rank  (store raw src, raw ew)
__global__ __launch_bounds__(256) void fill_k(const int* __restrict__ src, const int* __restrict__ dst,
                                              const float* __restrict__ ew,
                                              const int* __restrict__ row_ptr,
                                              const int* __restrict__ rank,
                                              int2* __restrict__ meta, int E) {
    int e = blockIdx.x * 256 + threadIdx.x;
    if (e < E) {
        int d = dst[e];
        int pos = row_ptr[d] + rank[e];
        meta[pos] = make_int2(src[e], __float_as_int(ew[e]));
    }
}

// per-node weighted degree from CSR rows (coalesced-ish, no atomics) -> dinv
__global__ __launch_bounds__(256) void deg_k(const int2* __restrict__ meta,
                                             const int* __restrict__ row_ptr,
                                             const int* __restrict__ cnt,
                                             float* __restrict__ dinv, int n) {
    int d = blockIdx.x * 256 + threadIdx.x;
    if (d < n) {
        int start = row_ptr[d];
        int c = cnt[d];
        float s = 1.0f;                    // self loop weight
        for (int j = 0; j < c; j++) s += __int_as_float(meta[start + j].y);
        dinv[d] = rsqrtf(s);
    }
}

// meta.w *= dinv[src]  (dinv[dst] applied at agg time)
__global__ __launch_bounds__(256) void scale_k(int2* __restrict__ meta,
                                               const float* __restrict__ dinv, int E) {
    int e = blockIdx.x * 256 + threadIdx.x;
    if (e < E) {
        int2 m = meta[e];
        float wn = __int_as_float(m.y) * dinv[m.x];
        ((int*)meta)[2 * e + 1] = __float_as_int(wn);
    }
}

// ---------------- fp32 GEMM: T[M,128] = A[M,K] @ W[K,128] ----------------
// BM=64, BN=128, BK=64, 256 threads, each thread 8x4 outputs.

__global__ __launch_bounds__(256) void gemm_k(const float* __restrict__ A, const float* __restrict__ W,
                                              float* __restrict__ T, int M, int K) {
    __shared__ float xs[64][68];
    __shared__ float ws[64][128];
    int tid = threadIdx.x;
    int row0 = blockIdx.x * 64;
    int tx = tid & 31;
    int ty = tid >> 5;
    float acc[8][4] = {};

    for (int k0 = 0; k0 < K; k0 += 64) {
        #pragma unroll
        for (int j = 0; j < 4; j++) {
            int idx = tid + j * 256;
            int r = idx >> 4;
            int c = (idx & 15) << 2;
            int gr = row0 + r;
            float4 v = make_float4(0.f, 0.f, 0.f, 0.f);
            if (gr < M) v = *(const float4*)(A + (size_t)gr * K + k0 + c);
            *(float4*)(&xs[r][c]) = v;
        }
        #pragma unroll
        for (int j = 0; j < 8; j++) {
            int idx = tid + j * 256;
            int kk = idx >> 5;
            int c = (idx & 31) << 2;
            *(float4*)(&ws[kk][c]) = *(const float4*)(W + (size_t)(k0 + kk) * 128 + c);
        }
        __syncthreads();
        #pragma unroll 8
        for (int k = 0; k < 64; k++) {
            float4 b = *(const float4*)(&ws[k][tx << 2]);
            float a[8];
            #pragma unroll
            for (int r = 0; r < 8; r++) a[r] = xs[ty * 8 + r][k];
            #pragma unroll
            for (int r = 0; r < 8; r++) {
                acc[r][0] = fmaf(a[r], b.x, acc[r][0]);
                acc[r][1] = fmaf(a[r], b.y, acc[r][1]);
                acc[r][2] = fmaf(a[r], b.z, acc[r][2]);
                acc[r][3] = fmaf(a[r], b.w, acc[r][3]);
            }
        }
        __syncthreads();
    }
    #pragma unroll
    for (int r = 0; r < 8; r++) {
        int gr = row0 + ty * 8 + r;
        if (gr < M) *(float4*)(T + (size_t)gr * 128 + (tx << 2)) = *(float4*)(acc[r]);
    }
}

// ---------------- aggregation + bias + relu ----------------

__global__ __launch_bounds__(128) void agg_k(const float* __restrict__ T, float* __restrict__ H,
                                             const int2* __restrict__ meta,
                                             const int* __restrict__ row_ptr, const int* __restrict__ cnt,
                                             const float* __restrict__ dinv, const float* __restrict__ bias,
                                             int n) {
    int d = blockIdx.x;
    int f = threadIdx.x;
    float nd = dinv[d];
    float acc = nd * T[(size_t)d * 128 + f];
    int start = row_ptr[d];
    int c = cnt[d];
    int j = 0;
    for (; j + 1 < c; j += 2) {
        int2 m0 = meta[start + j];
        int2 m1 = meta[start + j + 1];
        float t0 = T[(size_t)m0.x * 128 + f];
        float t1 = T[(size_t)m1.x * 128 + f];
        acc = fmaf(__int_as_float(m0.y), t0, acc);
        acc = fmaf(__int_as_float(m1.y), t1, acc);
    }
    if (j < c) {
        int2 m0 = meta[start + j];
        acc = fmaf(__int_as_float(m0.y), T[(size_t)m0.x * 128 + f], acc);
    }
    float v = fmaf(nd, acc, bias[f]);
    H[(size_t)d * 128 + f] = v > 0.f ? v : 0.f;
}

// ---------------- final FC(128->10) + softmax ----------------

__global__ __launch_bounds__(256) void fc_k(const float* __restrict__ Hb, const float* __restrict__ FW,
                                            const float* __restrict__ FB, float* __restrict__ out, int n) {
    __shared__ float fw[128 * 10];
    __shared__ float fb[16];
    int tid = threadIdx.x;
    for (int i = tid; i < 128 * 10; i += 256) fw[i] = FW[i];
    if (tid < 10) fb[tid] = FB[tid];
    __syncthreads();
    int wave = tid >> 6, lane = tid & 63;
    int r = blockIdx.x * 4 + wave;
    if (r >= n) return;
    float h0 = Hb[(size_t)r * 128 + lane];
    float h1 = Hb[(size_t)r * 128 + 64 + lane];
    float p[10];
    #pragma unroll
    for (int c = 0; c < 10; c++)
        p[c] = h0 * fw[lane * 10 + c] + h1 * fw[(64 + lane) * 10 + c];
    #pragma unroll
    for (int off = 32; off > 0; off >>= 1) {
        #pragma unroll
        for (int c = 0; c < 10; c++) p[c] += __shfl_xor(p[c], off);
    }
    float m = -1e30f;
    #pragma unroll
    for (int c = 0; c < 10; c++) { p[c] += fb[c]; m = fmaxf(m, p[c]); }
    float s = 0.f;
    float e[10];
    #pragma unroll
    for (int c = 0; c < 10; c++) { e[c] = __expf(p[c] - m); s += e[c]; }
    float inv = 1.f / s;
    if (lane < 10) out[(size_t)r * 10 + lane] = e[lane] * inv;
}

// ---------------- host ----------------

extern "C" void kernel_launch(void* const* d_in, const int* in_sizes, int n_in,
                              void* d_out, int out_size, void* d_ws, size_t ws_size,
                              hipStream_t stream) {
    const float* x  = (const float*)d_in[0];
    const int*   ei = (const int*)d_in[1];
    const float* ew = (const float*)d_in[2];
    const float* W1 = (const float*)d_in[3];
    const float* b1 = (const float*)d_in[4];
    const float* W2 = (const float*)d_in[5];
    const float* b2 = (const float*)d_in[6];
    const float* W3 = (const float*)d_in[7];
    const float* b3 = (const float*)d_in[8];
    const float* FW = (const float*)d_in[9];
    const float* FB = (const float*)d_in[10];
    float* out = (float*)d_out;

    int Hd = in_sizes[4];            // 128
    int F  = in_sizes[3] / Hd;       // 256
    int N  = in_sizes[0] / F;        // 50000
    int E  = in_sizes[1] / 2;        // 800000

    const int* src = ei;
    const int* dst = ei + E;

    char* ws = (char*)d_ws;
    size_t off = 0;
    auto alloc = [&](size_t bytes) -> void* {
        void* p = ws + off;
        off = (off + bytes + 255) & ~(size_t)255;
        return p;
    };
    float* dinv    = (float*)alloc((size_t)N * 4);
    int*   cnt     = (int*)alloc((size_t)N * 4);
    int*   row_ptr = (int*)alloc((size_t)N * 4);
    int*   rank    = (int*)alloc((size_t)E * 4);
    int*   bsum    = (int*)alloc(4096);
    int2*  meta    = (int2*)alloc((size_t)E * 8);
    float* T       = (float*)alloc((size_t)N * Hd * 4);
    float* Hbuf    = (float*)alloc((size_t)N * Hd * 4);

    int nb = (N + 1023) / 1024;

    hipMemsetAsync(cnt, 0, (size_t)N * 4, stream);
    rank_k<<<(E + 255) / 256, 256, 0, stream>>>(dst, cnt, rank, E);
    scan1_k<<<nb, 256, 0, stream>>>(cnt, bsum, N);
    scan2_k<<<1, 64, 0, stream>>>(bsum, nb);
    scan3_k<<<nb, 256, 0, stream>>>(cnt, bsum, row_ptr, N);
    fill_k<<<(E + 255) / 256, 256, 0, stream>>>(src, dst, ew, row_ptr, rank, meta, E);
    deg_k<<<(N + 255) / 256, 256, 0, stream>>>(meta, row_ptr, cnt, dinv, N);
    scale_k<<<(E + 255) / 256, 256, 0, stream>>>(meta, dinv, E);

    int gb = (N + 63) / 64;
    // layer 1
    gemm_k<<<gb, 256, 0, stream>>>(x, W1, T, N, F);
    agg_k<<<N, 128, 0, stream>>>(T, Hbuf, meta, row_ptr, cnt, dinv, b1, N);
    // layer 2
    gemm_k<<<gb, 256, 0, stream>>>(Hbuf, W2, T, N, Hd);
    agg_k<<<N, 128, 0, stream>>>(T, Hbuf, meta, row_ptr, cnt, dinv, b2, N);
    // layer 3
    gemm_k<<<gb, 256, 0, stream>>>(Hbuf, W3, T, N, Hd);
    agg_k<<<N, 128, 0, stream>>>(T, Hbuf, meta, row_ptr, cnt, dinv, b3, N);
    // FC + softmax
    fc_k<<<(N + 3) / 4, 256, 0, stream>>>(Hbuf, FW, FB, out, N);
}